// Round 3
// baseline (263.305 us; speedup 1.0000x reference)
//
#include <hip/hip_runtime.h>
#include <cstdint>
#include <cstddef>

#define I_DIM 4096
#define O_DIM 4096
#define RNK 32
#define NGRP 64
#define N_TOK 4096

typedef int v4i  __attribute__((ext_vector_type(4)));
typedef int v16i __attribute__((ext_vector_type(16)));

__device__ __forceinline__ int clamp_i8(float v) {
    int q = (int)rintf(v);           // round half to even, matches jnp.round
    q = q < -128 ? -128 : q;
    q = q > 127 ? 127 : q;
    return q;
}

// ---------------------------------------------------------------------------
// Kernel 1: dequantize W (int4 + group affine + SVD correction), compute
// per-output-row scale_w = max|W[o,:]|/127, write W_q int8 in [O, I].
// Single pass, r-outer rank loop: svd_up staged in LDS (broadcast reads),
// svd_down read as coalesced float4. W held in VGPRs (64 floats/thread).
// No tight launch-bounds cap: let the allocator take ~110 VGPRs w/o spill.
// ---------------------------------------------------------------------------
#define BO 4

__global__ __launch_bounds__(256) void quant_w_kernel(
    const int* __restrict__ w_packed, const float* __restrict__ svd_up,
    const float* __restrict__ svd_down, const float* __restrict__ scale,
    const float* __restrict__ zp, char* __restrict__ w_q,
    float* __restrict__ scale_w)
{
    __shared__ float s_sc[BO][NGRP];
    __shared__ float s_zp[BO][NGRP];
    __shared__ float s_up[RNK][BO];
    __shared__ float s_red[BO][4];
    __shared__ float s_sw[BO];

    const int tid = threadIdx.x;
    const int o0 = blockIdx.x * BO;

    if (tid < RNK * BO) {
        const int r = tid >> 2, ro = tid & 3;
        s_up[r][ro] = svd_up[(size_t)(o0 + ro) * RNK + r];
    }
    for (int t = tid; t < BO * NGRP; t += 256) {
        s_sc[t >> 6][t & 63] = scale[(size_t)(o0 + (t >> 6)) * NGRP + (t & 63)];
        s_zp[t >> 6][t & 63] = zp[(size_t)(o0 + (t >> 6)) * NGRP + (t & 63)];
    }
    __syncthreads();

    float W[4][BO][4];     // [col-quad jq][row ro][col-in-quad]

    // init with affine dequant of the int4 values
#pragma unroll
    for (int jq = 0; jq < 4; jq++) {
        const int q = tid + 256 * jq;    // col-quad index, 0..1023
        const int g = q >> 4;            // group (4 cols same group)
#pragma unroll
        for (int ro = 0; ro < BO; ro++) {
            const int2 b2 = *(const int2*)&w_packed[(size_t)(o0 + ro) * (I_DIM / 2) + 2 * q];
            const float sc = s_sc[ro][g], z = s_zp[ro][g];
            W[jq][ro][0] = ((float)(b2.x & 0xF) - z) * sc;
            W[jq][ro][1] = ((float)((b2.x >> 4) & 0xF) - z) * sc;
            W[jq][ro][2] = ((float)(b2.y & 0xF) - z) * sc;
            W[jq][ro][3] = ((float)((b2.y >> 4) & 0xF) - z) * sc;
        }
    }

    // rank-32 SVD correction, r-outer: 4 broadcast u-reads + 4 float4 loads per r
#pragma unroll 2
    for (int r = 0; r < RNK; r++) {
        const float4* dr = (const float4*)(svd_down + (size_t)r * I_DIM);
        float u[BO];
#pragma unroll
        for (int ro = 0; ro < BO; ro++) u[ro] = s_up[r][ro];
        float4 d[4];
#pragma unroll
        for (int jq = 0; jq < 4; jq++) d[jq] = dr[tid + 256 * jq];
#pragma unroll
        for (int jq = 0; jq < 4; jq++) {
#pragma unroll
            for (int ro = 0; ro < BO; ro++) {
                W[jq][ro][0] += u[ro] * d[jq].x;
                W[jq][ro][1] += u[ro] * d[jq].y;
                W[jq][ro][2] += u[ro] * d[jq].z;
                W[jq][ro][3] += u[ro] * d[jq].w;
            }
        }
    }

    float vmax[BO];
#pragma unroll
    for (int ro = 0; ro < BO; ro++) vmax[ro] = 0.0f;
#pragma unroll
    for (int jq = 0; jq < 4; jq++)
#pragma unroll
        for (int ro = 0; ro < BO; ro++)
            vmax[ro] = fmaxf(vmax[ro],
                fmaxf(fmaxf(fabsf(W[jq][ro][0]), fabsf(W[jq][ro][1])),
                      fmaxf(fabsf(W[jq][ro][2]), fabsf(W[jq][ro][3]))));

    // block-wide max per row
    const int lane = tid & 63, wv = tid >> 6;
#pragma unroll
    for (int ro = 0; ro < BO; ro++) {
        float m = vmax[ro];
        for (int off = 32; off > 0; off >>= 1)
            m = fmaxf(m, __shfl_down(m, off, 64));
        if (lane == 0) s_red[ro][wv] = m;
    }
    __syncthreads();
    if (tid < BO) {
        const float m = fmaxf(fmaxf(s_red[tid][0], s_red[tid][1]),
                              fmaxf(s_red[tid][2], s_red[tid][3]));
        const float sw = m / 127.0f;
        scale_w[o0 + tid] = sw;
        s_sw[tid] = sw;
    }
    __syncthreads();

    float inv[BO];
#pragma unroll
    for (int ro = 0; ro < BO; ro++) inv[ro] = 1.0f / s_sw[ro];

    // quantize from registers, pack 4 int8 per int store
#pragma unroll
    for (int jq = 0; jq < 4; jq++) {
        const int q = tid + 256 * jq;
#pragma unroll
        for (int ro = 0; ro < BO; ro++) {
            const int q0 = clamp_i8(W[jq][ro][0] * inv[ro]);
            const int q1 = clamp_i8(W[jq][ro][1] * inv[ro]);
            const int q2 = clamp_i8(W[jq][ro][2] * inv[ro]);
            const int q3 = clamp_i8(W[jq][ro][3] * inv[ro]);
            ((int*)w_q)[(size_t)(o0 + ro) * (I_DIM / 4) + q] =
                (q0 & 0xFF) | ((q1 & 0xFF) << 8) | ((q2 & 0xFF) << 16) | ((q3 & 0xFF) << 24);
        }
    }
}

// ---------------------------------------------------------------------------
// Kernel 2: per-token dynamic activation quant. One block per row.
// ---------------------------------------------------------------------------
__global__ __launch_bounds__(256) void quant_x_kernel(
    const float* __restrict__ x, char* __restrict__ x_q,
    float* __restrict__ scale_x)
{
    const int n = blockIdx.x;
    const int tid = threadIdx.x;
    const float4* xr = (const float4*)(x + (size_t)n * I_DIM);
    float4 v[4];
    float m = 0.0f;
#pragma unroll
    for (int j = 0; j < 4; j++) {
        v[j] = xr[tid + 256 * j];
        m = fmaxf(m, fmaxf(fmaxf(fabsf(v[j].x), fabsf(v[j].y)),
                           fmaxf(fabsf(v[j].z), fabsf(v[j].w))));
    }
    __shared__ float s_red[4];
    __shared__ float s_sx;
    for (int off = 32; off > 0; off >>= 1)
        m = fmaxf(m, __shfl_down(m, off, 64));
    if ((tid & 63) == 0) s_red[tid >> 6] = m;
    __syncthreads();
    if (tid == 0) {
        const float mm = fmaxf(fmaxf(s_red[0], s_red[1]),
                               fmaxf(s_red[2], s_red[3]));
        const float sx = mm / 127.0f;
        scale_x[n] = sx;
        s_sx = sx;
    }
    __syncthreads();
    const float sx = s_sx;
    int* outw = (int*)(x_q + (size_t)n * I_DIM);
#pragma unroll
    for (int j = 0; j < 4; j++) {
        const int q0 = clamp_i8(v[j].x / sx);
        const int q1 = clamp_i8(v[j].y / sx);
        const int q2 = clamp_i8(v[j].z / sx);
        const int q3 = clamp_i8(v[j].w / sx);
        outw[tid + 256 * j] =
            (q0 & 0xFF) | ((q1 & 0xFF) << 8) | ((q2 & 0xFF) << 16) | ((q3 & 0xFF) << 24);
    }
}

// ---------------------------------------------------------------------------
// Kernel 3: int8 GEMM, 128x128x128B tile, mfma_i32_32x32x32_i8.
// 4 waves in a 2x2 grid, each computing a 64x64 patch as 2x2 32x32 tiles.
// Same global_load_lds width-16 staging + XOR K-chunk swizzle as before
// (measured conflict-free). Half the MFMA instruction count of 16x16x64.
// ---------------------------------------------------------------------------
#define BM 128
#define BN 128
#define BK 128

__global__ __launch_bounds__(256) void gemm_i8_kernel(
    const char* __restrict__ x_q, const char* __restrict__ w_q,
    const float* __restrict__ scale_x, const float* __restrict__ scale_w,
    const float* __restrict__ bias, float* __restrict__ out)
{
    __shared__ v4i As4[BM * BK / 16];
    __shared__ v4i Bs4[BN * BK / 16];
    char* As = (char*)As4;
    char* Bs = (char*)Bs4;

    const int tid = threadIdx.x;
    const int bm0 = blockIdx.x * BM;
    const int bn0 = blockIdx.y * BN;
    const int lane = tid & 63, wv = tid >> 6;
    const int wm = wv & 1, wn = wv >> 1;
    const int l31 = lane & 31, h = lane >> 5;

    v16i acc[2][2];
#pragma unroll
    for (int mt = 0; mt < 2; mt++)
#pragma unroll
        for (int nt = 0; nt < 2; nt++)
            acc[mt][nt] = (v16i)(0);

    for (int kk = 0; kk < I_DIM / BK; kk++) {
        const int k0 = kk * BK;
        // stage A (128x128B) and B^T (128x128B): 8 chunks of 16B per thread.
        // LDS slot c holds logical chunk (row=c>>3, kc=(c&7)^(row&7)).
#pragma unroll
        for (int j = 0; j < 4; j++) {
            const int c = tid + 256 * j;
            const int row = c >> 3;
            const int kc = (c & 7) ^ (row & 7);
            const char* ga = x_q + (size_t)(bm0 + row) * I_DIM + k0 + kc * 16;
            __builtin_amdgcn_global_load_lds(
                (const __attribute__((address_space(1))) unsigned int*)ga,
                (__attribute__((address_space(3))) unsigned int*)(As + c * 16),
                16, 0, 0);
            const char* gb = w_q + (size_t)(bn0 + row) * I_DIM + k0 + kc * 16;
            __builtin_amdgcn_global_load_lds(
                (const __attribute__((address_space(1))) unsigned int*)gb,
                (__attribute__((address_space(3))) unsigned int*)(Bs + c * 16),
                16, 0, 0);
        }
        __syncthreads();
        // A-operand layout (i8 32x32x32): m = lane&31, k = (lane>>5)*16 + j
#pragma unroll
        for (int s = 0; s < 4; s++) {
            v4i af[2], bf[2];
#pragma unroll
            for (int mt = 0; mt < 2; mt++) {
                const int row = wm * 64 + mt * 32 + l31;
                const int kc = (s * 2 + h) ^ (row & 7);
                af[mt] = *(const v4i*)(As + row * BK + kc * 16);
            }
#pragma unroll
            for (int nt = 0; nt < 2; nt++) {
                const int row = wn * 64 + nt * 32 + l31;
                const int kc = (s * 2 + h) ^ (row & 7);
                bf[nt] = *(const v4i*)(Bs + row * BK + kc * 16);
            }
#pragma unroll
            for (int mt = 0; mt < 2; mt++)
#pragma unroll
                for (int nt = 0; nt < 2; nt++)
                    acc[mt][nt] = __builtin_amdgcn_mfma_i32_32x32x32_i8(
                        af[mt], bf[nt], acc[mt][nt], 0, 0, 0);
        }
        __syncthreads();
    }

    // epilogue: 32x32 C/D layout: col = lane&31, row = (reg&3)+8*(reg>>2)+4*(lane>>5)
#pragma unroll
    for (int mt = 0; mt < 2; mt++) {
        const int rbase = bm0 + wm * 64 + mt * 32 + 4 * h;
        float sx[16];
#pragma unroll
        for (int reg = 0; reg < 16; reg++)
            sx[reg] = scale_x[rbase + (reg & 3) + 8 * (reg >> 2)];
#pragma unroll
        for (int nt = 0; nt < 2; nt++) {
            const int oc = bn0 + wn * 64 + nt * 32 + l31;
            const float sw = scale_w[oc];
            const float bs = bias[oc];
#pragma unroll
            for (int reg = 0; reg < 16; reg++) {
                const int rr = rbase + (reg & 3) + 8 * (reg >> 2);
                out[(size_t)rr * O_DIM + oc] =
                    (float)acc[mt][nt][reg] * sx[reg] * sw + bs;
            }
        }
    }
}

// ---------------------------------------------------------------------------
extern "C" void kernel_launch(void* const* d_in, const int* in_sizes, int n_in,
                              void* d_out, int out_size, void* d_ws, size_t ws_size,
                              hipStream_t stream) {
    const float* x        = (const float*)d_in[0];
    const int*   w_packed = (const int*)d_in[1];
    const float* svd_up   = (const float*)d_in[2];
    const float* svd_down = (const float*)d_in[3];
    const float* scale    = (const float*)d_in[4];
    const float* zp       = (const float*)d_in[5];
    const float* bias     = (const float*)d_in[6];
    float* out = (float*)d_out;

    char* ws = (char*)d_ws;
    char*  w_q     = ws;                                   // 16 MB int8 [O, I]
    char*  x_q     = ws + ((size_t)16 << 20);              // 16 MB int8 [N, I]
    float* scale_w = (float*)(ws + ((size_t)32 << 20));    // 16 KB
    float* scale_x = (float*)(ws + ((size_t)32 << 20) + 16384);  // 16 KB

    quant_w_kernel<<<O_DIM / BO, 256, 0, stream>>>(w_packed, svd_up, svd_down,
                                                   scale, zp, w_q, scale_w);
    quant_x_kernel<<<N_TOK, 256, 0, stream>>>(x, x_q, scale_x);
    gemm_i8_kernel<<<dim3(N_TOK / BM, O_DIM / BN), 256, 0, stream>>>(
        x_q, w_q, scale_x, scale_w, bias, out);
}

// Round 4
// 256.271 us; speedup vs baseline: 1.0274x; 1.0274x over previous
//
#include <hip/hip_runtime.h>
#include <cstdint>
#include <cstddef>

#define I_DIM 4096
#define O_DIM 4096
#define RNK 32
#define NGRP 64
#define N_TOK 4096

typedef int v4i  __attribute__((ext_vector_type(4)));
typedef int v16i __attribute__((ext_vector_type(16)));

__device__ __forceinline__ int clamp_i8(float v) {
    int q = (int)rintf(v);           // round half to even, matches jnp.round
    q = q < -128 ? -128 : q;
    q = q > 127 ? 127 : q;
    return q;
}

// ---------------------------------------------------------------------------
// Fused quant kernel. Blocks [0, N_TOK): per-token activation quant
// (memory-bound). Blocks [N_TOK, N_TOK + O_DIM/BO): weight dequant+quant
// (VALU-bound, round-2 jq-outer structure — measured faster than r-outer).
// Fusing lets the two populations co-schedule across CUs instead of
// serializing through two launches.
// ---------------------------------------------------------------------------
#define BO 4

__global__ __launch_bounds__(256, 4) void quant_fused_kernel(
    const float* __restrict__ x, char* __restrict__ x_q,
    float* __restrict__ scale_x,
    const int* __restrict__ w_packed, const float* __restrict__ svd_up,
    const float* __restrict__ svd_down, const float* __restrict__ scale,
    const float* __restrict__ zp, char* __restrict__ w_q,
    float* __restrict__ scale_w)
{
    const int tid = threadIdx.x;

    if (blockIdx.x < N_TOK) {
        // ---------------- activation quant: one block per token row --------
        const int n = blockIdx.x;
        const float4* xr = (const float4*)(x + (size_t)n * I_DIM);
        float4 v[4];
        float m = 0.0f;
#pragma unroll
        for (int j = 0; j < 4; j++) {
            v[j] = xr[tid + 256 * j];
            m = fmaxf(m, fmaxf(fmaxf(fabsf(v[j].x), fabsf(v[j].y)),
                               fmaxf(fabsf(v[j].z), fabsf(v[j].w))));
        }
        __shared__ float sx_red[4];
        __shared__ float s_sx;
        for (int off = 32; off > 0; off >>= 1)
            m = fmaxf(m, __shfl_down(m, off, 64));
        if ((tid & 63) == 0) sx_red[tid >> 6] = m;
        __syncthreads();
        if (tid == 0) {
            const float mm = fmaxf(fmaxf(sx_red[0], sx_red[1]),
                                   fmaxf(sx_red[2], sx_red[3]));
            const float sx = mm / 127.0f;
            scale_x[n] = sx;
            s_sx = sx;
        }
        __syncthreads();
        const float sx = s_sx;
        int* outw = (int*)(x_q + (size_t)n * I_DIM);
#pragma unroll
        for (int j = 0; j < 4; j++) {
            const int q0 = clamp_i8(v[j].x / sx);
            const int q1 = clamp_i8(v[j].y / sx);
            const int q2 = clamp_i8(v[j].z / sx);
            const int q3 = clamp_i8(v[j].w / sx);
            outw[tid + 256 * j] =
                (q0 & 0xFF) | ((q1 & 0xFF) << 8) | ((q2 & 0xFF) << 16) | ((q3 & 0xFF) << 24);
        }
        return;
    }

    // ---------------- weight dequant + dynamic per-row quant ---------------
    const int o0 = (blockIdx.x - N_TOK) * BO;

    __shared__ float s_sc[BO][NGRP];
    __shared__ float s_zp[BO][NGRP];
    __shared__ float s_red[BO][4];
    __shared__ float s_sw[BO];

    for (int t = tid; t < BO * NGRP; t += 256) {
        s_sc[t >> 6][t & 63] = scale[(size_t)(o0 + (t >> 6)) * NGRP + (t & 63)];
        s_zp[t >> 6][t & 63] = zp[(size_t)(o0 + (t >> 6)) * NGRP + (t & 63)];
    }
    __syncthreads();

    float W[4][BO][4];     // [col-quad jq][row ro][col-in-quad]
    float vmax[BO];
#pragma unroll
    for (int ro = 0; ro < BO; ro++) vmax[ro] = 0.0f;

#pragma unroll
    for (int jq = 0; jq < 4; jq++) {
        const int q = tid + 256 * jq;    // col-quad index, 0..1023
        const int i = 4 * q;             // first column of the quad
        const int g = q >> 4;            // group (4 cols same group)

        // init with affine dequant of the 4 int4 values
#pragma unroll
        for (int ro = 0; ro < BO; ro++) {
            const int2 b2 = *(const int2*)&w_packed[(size_t)(o0 + ro) * (I_DIM / 2) + 2 * q];
            const float sc = s_sc[ro][g], z = s_zp[ro][g];
            W[jq][ro][0] = ((float)(b2.x & 0xF) - z) * sc;
            W[jq][ro][1] = ((float)((b2.x >> 4) & 0xF) - z) * sc;
            W[jq][ro][2] = ((float)(b2.y & 0xF) - z) * sc;
            W[jq][ro][3] = ((float)((b2.y >> 4) & 0xF) - z) * sc;
        }

        // rank-32 SVD correction; svd_up loads are block-uniform -> SGPR
#pragma unroll 4
        for (int r = 0; r < RNK; r++) {
            const float4 d = *(const float4*)&svd_down[(size_t)r * I_DIM + i];
#pragma unroll
            for (int ro = 0; ro < BO; ro++) {
                const float u = svd_up[(size_t)(o0 + ro) * RNK + r];
                W[jq][ro][0] += u * d.x;
                W[jq][ro][1] += u * d.y;
                W[jq][ro][2] += u * d.z;
                W[jq][ro][3] += u * d.w;
            }
        }

#pragma unroll
        for (int ro = 0; ro < BO; ro++) {
            vmax[ro] = fmaxf(vmax[ro],
                fmaxf(fmaxf(fabsf(W[jq][ro][0]), fabsf(W[jq][ro][1])),
                      fmaxf(fabsf(W[jq][ro][2]), fabsf(W[jq][ro][3]))));
        }
    }

    // block-wide max per row
    const int lane = tid & 63, wv = tid >> 6;
#pragma unroll
    for (int ro = 0; ro < BO; ro++) {
        float m = vmax[ro];
        for (int off = 32; off > 0; off >>= 1)
            m = fmaxf(m, __shfl_down(m, off, 64));
        if (lane == 0) s_red[ro][wv] = m;
    }
    __syncthreads();
    if (tid < BO) {
        const float m = fmaxf(fmaxf(s_red[tid][0], s_red[tid][1]),
                              fmaxf(s_red[tid][2], s_red[tid][3]));
        const float sw = m / 127.0f;
        scale_w[o0 + tid] = sw;
        s_sw[tid] = sw;
    }
    __syncthreads();

    float inv[BO];
#pragma unroll
    for (int ro = 0; ro < BO; ro++) inv[ro] = 1.0f / s_sw[ro];

    // quantize from registers, pack 4 int8 per int store
#pragma unroll
    for (int jq = 0; jq < 4; jq++) {
        const int q = tid + 256 * jq;
#pragma unroll
        for (int ro = 0; ro < BO; ro++) {
            const int q0 = clamp_i8(W[jq][ro][0] * inv[ro]);
            const int q1 = clamp_i8(W[jq][ro][1] * inv[ro]);
            const int q2 = clamp_i8(W[jq][ro][2] * inv[ro]);
            const int q3 = clamp_i8(W[jq][ro][3] * inv[ro]);
            ((int*)w_q)[(size_t)(o0 + ro) * (I_DIM / 4) + q] =
                (q0 & 0xFF) | ((q1 & 0xFF) << 8) | ((q2 & 0xFF) << 16) | ((q3 & 0xFF) << 24);
        }
    }
}

// ---------------------------------------------------------------------------
// Kernel 2: int8 GEMM, 128x128x128B tile, mfma_i32_32x32x32_i8 (round-3
// version, 89 us measured — faster than the conflict-free 16x16x64 variant
// despite 8.4M LDS bank-conflict cycles).
// ---------------------------------------------------------------------------
#define BM 128
#define BN 128
#define BK 128

__global__ __launch_bounds__(256) void gemm_i8_kernel(
    const char* __restrict__ x_q, const char* __restrict__ w_q,
    const float* __restrict__ scale_x, const float* __restrict__ scale_w,
    const float* __restrict__ bias, float* __restrict__ out)
{
    __shared__ v4i As4[BM * BK / 16];
    __shared__ v4i Bs4[BN * BK / 16];
    char* As = (char*)As4;
    char* Bs = (char*)Bs4;

    const int tid = threadIdx.x;
    const int bm0 = blockIdx.x * BM;
    const int bn0 = blockIdx.y * BN;
    const int lane = tid & 63, wv = tid >> 6;
    const int wm = wv & 1, wn = wv >> 1;
    const int l31 = lane & 31, h = lane >> 5;

    v16i acc[2][2];
#pragma unroll
    for (int mt = 0; mt < 2; mt++)
#pragma unroll
        for (int nt = 0; nt < 2; nt++)
            acc[mt][nt] = (v16i)(0);

    for (int kk = 0; kk < I_DIM / BK; kk++) {
        const int k0 = kk * BK;
        // stage A (128x128B) and B^T (128x128B): 8 chunks of 16B per thread.
        // LDS slot c holds logical chunk (row=c>>3, kc=(c&7)^(row&7)).
#pragma unroll
        for (int j = 0; j < 4; j++) {
            const int c = tid + 256 * j;
            const int row = c >> 3;
            const int kc = (c & 7) ^ (row & 7);
            const char* ga = x_q + (size_t)(bm0 + row) * I_DIM + k0 + kc * 16;
            __builtin_amdgcn_global_load_lds(
                (const __attribute__((address_space(1))) unsigned int*)ga,
                (__attribute__((address_space(3))) unsigned int*)(As + c * 16),
                16, 0, 0);
            const char* gb = w_q + (size_t)(bn0 + row) * I_DIM + k0 + kc * 16;
            __builtin_amdgcn_global_load_lds(
                (const __attribute__((address_space(1))) unsigned int*)gb,
                (__attribute__((address_space(3))) unsigned int*)(Bs + c * 16),
                16, 0, 0);
        }
        __syncthreads();
        // A-operand layout (i8 32x32x32): m = lane&31, k = (lane>>5)*16 + j
#pragma unroll
        for (int s = 0; s < 4; s++) {
            v4i af[2], bf[2];
#pragma unroll
            for (int mt = 0; mt < 2; mt++) {
                const int row = wm * 64 + mt * 32 + l31;
                const int kc = (s * 2 + h) ^ (row & 7);
                af[mt] = *(const v4i*)(As + row * BK + kc * 16);
            }
#pragma unroll
            for (int nt = 0; nt < 2; nt++) {
                const int row = wn * 64 + nt * 32 + l31;
                const int kc = (s * 2 + h) ^ (row & 7);
                bf[nt] = *(const v4i*)(Bs + row * BK + kc * 16);
            }
#pragma unroll
            for (int mt = 0; mt < 2; mt++)
#pragma unroll
                for (int nt = 0; nt < 2; nt++)
                    acc[mt][nt] = __builtin_amdgcn_mfma_i32_32x32x32_i8(
                        af[mt], bf[nt], acc[mt][nt], 0, 0, 0);
        }
        __syncthreads();
    }

    // epilogue: 32x32 C/D layout: col = lane&31, row = (reg&3)+8*(reg>>2)+4*(lane>>5)
#pragma unroll
    for (int mt = 0; mt < 2; mt++) {
        const int rbase = bm0 + wm * 64 + mt * 32 + 4 * h;
        float sx[16];
#pragma unroll
        for (int reg = 0; reg < 16; reg++)
            sx[reg] = scale_x[rbase + (reg & 3) + 8 * (reg >> 2)];
#pragma unroll
        for (int nt = 0; nt < 2; nt++) {
            const int oc = bn0 + wn * 64 + nt * 32 + l31;
            const float sw = scale_w[oc];
            const float bs = bias[oc];
#pragma unroll
            for (int reg = 0; reg < 16; reg++) {
                const int rr = rbase + (reg & 3) + 8 * (reg >> 2);
                out[(size_t)rr * O_DIM + oc] =
                    (float)acc[mt][nt][reg] * sx[reg] * sw + bs;
            }
        }
    }
}

// ---------------------------------------------------------------------------
extern "C" void kernel_launch(void* const* d_in, const int* in_sizes, int n_in,
                              void* d_out, int out_size, void* d_ws, size_t ws_size,
                              hipStream_t stream) {
    const float* x        = (const float*)d_in[0];
    const int*   w_packed = (const int*)d_in[1];
    const float* svd_up   = (const float*)d_in[2];
    const float* svd_down = (const float*)d_in[3];
    const float* scale    = (const float*)d_in[4];
    const float* zp       = (const float*)d_in[5];
    const float* bias     = (const float*)d_in[6];
    float* out = (float*)d_out;

    char* ws = (char*)d_ws;
    char*  w_q     = ws;                                   // 16 MB int8 [O, I]
    char*  x_q     = ws + ((size_t)16 << 20);              // 16 MB int8 [N, I]
    float* scale_w = (float*)(ws + ((size_t)32 << 20));    // 16 KB
    float* scale_x = (float*)(ws + ((size_t)32 << 20) + 16384);  // 16 KB

    quant_fused_kernel<<<N_TOK + O_DIM / BO, 256, 0, stream>>>(
        x, x_q, scale_x, w_packed, svd_up, svd_down, scale, zp, w_q, scale_w);
    gemm_i8_kernel<<<dim3(N_TOK / BM, O_DIM / BN), 256, 0, stream>>>(
        x_q, w_q, scale_x, scale_w, bias, out);
}

// Round 5
// 254.469 us; speedup vs baseline: 1.0347x; 1.0071x over previous
//
#include <hip/hip_runtime.h>
#include <cstdint>
#include <cstddef>

#define I_DIM 4096
#define O_DIM 4096
#define RNK 32
#define NGRP 64
#define N_TOK 4096

typedef int v4i  __attribute__((ext_vector_type(4)));
typedef int v16i __attribute__((ext_vector_type(16)));

__device__ __forceinline__ int clamp_i8(float v) {
    int q = (int)rintf(v);           // round half to even, matches jnp.round
    q = q < -128 ? -128 : q;
    q = q > 127 ? 127 : q;
    return q;
}

// ---------------------------------------------------------------------------
// Kernel 1: weight dequant + dynamic per-row int8 quant (round-2 body,
// measured best). BO=4 rows/block, jq-outer, W held in VGPRs, svd_up via
// block-uniform global loads -> SGPR.
// ---------------------------------------------------------------------------
#define BO 4

__global__ __launch_bounds__(256, 4) void quant_w_kernel(
    const int* __restrict__ w_packed, const float* __restrict__ svd_up,
    const float* __restrict__ svd_down, const float* __restrict__ scale,
    const float* __restrict__ zp, char* __restrict__ w_q,
    float* __restrict__ scale_w)
{
    __shared__ float s_sc[BO][NGRP];
    __shared__ float s_zp[BO][NGRP];
    __shared__ float s_red[BO][4];
    __shared__ float s_sw[BO];

    const int tid = threadIdx.x;
    const int o0 = blockIdx.x * BO;

    for (int t = tid; t < BO * NGRP; t += 256) {
        s_sc[t >> 6][t & 63] = scale[(size_t)(o0 + (t >> 6)) * NGRP + (t & 63)];
        s_zp[t >> 6][t & 63] = zp[(size_t)(o0 + (t >> 6)) * NGRP + (t & 63)];
    }
    __syncthreads();

    float W[4][BO][4];     // [col-quad jq][row ro][col-in-quad]
    float vmax[BO];
#pragma unroll
    for (int ro = 0; ro < BO; ro++) vmax[ro] = 0.0f;

#pragma unroll
    for (int jq = 0; jq < 4; jq++) {
        const int q = tid + 256 * jq;    // col-quad index, 0..1023
        const int i = 4 * q;             // first column of the quad
        const int g = q >> 4;            // group (4 cols same group)

        // init with affine dequant of the 4 int4 values
#pragma unroll
        for (int ro = 0; ro < BO; ro++) {
            const int2 b2 = *(const int2*)&w_packed[(size_t)(o0 + ro) * (I_DIM / 2) + 2 * q];
            const float sc = s_sc[ro][g], z = s_zp[ro][g];
            W[jq][ro][0] = ((float)(b2.x & 0xF) - z) * sc;
            W[jq][ro][1] = ((float)((b2.x >> 4) & 0xF) - z) * sc;
            W[jq][ro][2] = ((float)(b2.y & 0xF) - z) * sc;
            W[jq][ro][3] = ((float)((b2.y >> 4) & 0xF) - z) * sc;
        }

        // rank-32 SVD correction; svd_up loads are block-uniform -> SGPR
#pragma unroll 4
        for (int r = 0; r < RNK; r++) {
            const float4 d = *(const float4*)&svd_down[(size_t)r * I_DIM + i];
#pragma unroll
            for (int ro = 0; ro < BO; ro++) {
                const float u = svd_up[(size_t)(o0 + ro) * RNK + r];
                W[jq][ro][0] += u * d.x;
                W[jq][ro][1] += u * d.y;
                W[jq][ro][2] += u * d.z;
                W[jq][ro][3] += u * d.w;
            }
        }

#pragma unroll
        for (int ro = 0; ro < BO; ro++) {
            vmax[ro] = fmaxf(vmax[ro],
                fmaxf(fmaxf(fabsf(W[jq][ro][0]), fabsf(W[jq][ro][1])),
                      fmaxf(fabsf(W[jq][ro][2]), fabsf(W[jq][ro][3]))));
        }
    }

    // block-wide max per row
    const int lane = tid & 63, wv = tid >> 6;
#pragma unroll
    for (int ro = 0; ro < BO; ro++) {
        float m = vmax[ro];
        for (int off = 32; off > 0; off >>= 1)
            m = fmaxf(m, __shfl_down(m, off, 64));
        if (lane == 0) s_red[ro][wv] = m;
    }
    __syncthreads();
    if (tid < BO) {
        const float m = fmaxf(fmaxf(s_red[tid][0], s_red[tid][1]),
                              fmaxf(s_red[tid][2], s_red[tid][3]));
        const float sw = m / 127.0f;
        scale_w[o0 + tid] = sw;
        s_sw[tid] = sw;
    }
    __syncthreads();

    float inv[BO];
#pragma unroll
    for (int ro = 0; ro < BO; ro++) inv[ro] = 1.0f / s_sw[ro];

    // quantize from registers, pack 4 int8 per int store
#pragma unroll
    for (int jq = 0; jq < 4; jq++) {
        const int q = tid + 256 * jq;
#pragma unroll
        for (int ro = 0; ro < BO; ro++) {
            const int q0 = clamp_i8(W[jq][ro][0] * inv[ro]);
            const int q1 = clamp_i8(W[jq][ro][1] * inv[ro]);
            const int q2 = clamp_i8(W[jq][ro][2] * inv[ro]);
            const int q3 = clamp_i8(W[jq][ro][3] * inv[ro]);
            ((int*)w_q)[(size_t)(o0 + ro) * (I_DIM / 4) + q] =
                (q0 & 0xFF) | ((q1 & 0xFF) << 8) | ((q2 & 0xFF) << 16) | ((q3 & 0xFF) << 24);
        }
    }
}

// ---------------------------------------------------------------------------
// Kernel 2: per-token dynamic activation quant. One block per row.
// ---------------------------------------------------------------------------
__global__ __launch_bounds__(256) void quant_x_kernel(
    const float* __restrict__ x, char* __restrict__ x_q,
    float* __restrict__ scale_x)
{
    const int n = blockIdx.x;
    const int tid = threadIdx.x;
    const float4* xr = (const float4*)(x + (size_t)n * I_DIM);
    float4 v[4];
    float m = 0.0f;
#pragma unroll
    for (int j = 0; j < 4; j++) {
        v[j] = xr[tid + 256 * j];
        m = fmaxf(m, fmaxf(fmaxf(fabsf(v[j].x), fabsf(v[j].y)),
                           fmaxf(fabsf(v[j].z), fabsf(v[j].w))));
    }
    __shared__ float s_red[4];
    __shared__ float s_sx;
    for (int off = 32; off > 0; off >>= 1)
        m = fmaxf(m, __shfl_down(m, off, 64));
    if ((tid & 63) == 0) s_red[tid >> 6] = m;
    __syncthreads();
    if (tid == 0) {
        const float mm = fmaxf(fmaxf(s_red[0], s_red[1]),
                               fmaxf(s_red[2], s_red[3]));
        const float sx = mm / 127.0f;
        scale_x[n] = sx;
        s_sx = sx;
    }
    __syncthreads();
    const float sx = s_sx;
    int* outw = (int*)(x_q + (size_t)n * I_DIM);
#pragma unroll
    for (int j = 0; j < 4; j++) {
        const int q0 = clamp_i8(v[j].x / sx);
        const int q1 = clamp_i8(v[j].y / sx);
        const int q2 = clamp_i8(v[j].z / sx);
        const int q3 = clamp_i8(v[j].w / sx);
        outw[tid + 256 * j] =
            (q0 & 0xFF) | ((q1 & 0xFF) << 8) | ((q2 & 0xFF) << 16) | ((q3 & 0xFF) << 24);
    }
}

// ---------------------------------------------------------------------------
// Kernel 3: int8 GEMM, 128x128x128B tile, mfma_i32_32x32x32_i8, 1-D grid
// with XCD-aware swizzle: round-robin dispatch puts id&7 on XCD (id&7);
// each XCD gets a dedicated 4-tile bn band (512 KB B working set, L2-
// resident) and sweeps bm within it -> B re-fetch from HBM collapses.
// ---------------------------------------------------------------------------
#define BM 128
#define BN 128
#define BK 128

__global__ __launch_bounds__(256) void gemm_i8_kernel(
    const char* __restrict__ x_q, const char* __restrict__ w_q,
    const float* __restrict__ scale_x, const float* __restrict__ scale_w,
    const float* __restrict__ bias, float* __restrict__ out)
{
    __shared__ v4i As4[BM * BK / 16];
    __shared__ v4i Bs4[BN * BK / 16];
    char* As = (char*)As4;
    char* Bs = (char*)Bs4;

    const int tid = threadIdx.x;
    // XCD-aware swizzle: xcd = id&7 owns bn tiles [xcd*4, xcd*4+4);
    // s>>5 picks the bn within the band, s&31 sweeps bm (B-tile reused
    // across 32 consecutive same-XCD blocks).
    const int id = blockIdx.x;
    const int xcd = id & 7;
    const int s_lin = id >> 3;                 // 0..127
    const int bm0 = (s_lin & 31) * BM;
    const int bn0 = (xcd * 4 + (s_lin >> 5)) * BN;

    const int lane = tid & 63, wv = tid >> 6;
    const int wm = wv & 1, wn = wv >> 1;
    const int l31 = lane & 31, h = lane >> 5;

    v16i acc[2][2];
#pragma unroll
    for (int mt = 0; mt < 2; mt++)
#pragma unroll
        for (int nt = 0; nt < 2; nt++)
            acc[mt][nt] = (v16i)(0);

    for (int kk = 0; kk < I_DIM / BK; kk++) {
        const int k0 = kk * BK;
        // stage A (128x128B) and B^T (128x128B): 8 chunks of 16B per thread.
        // LDS slot c holds logical chunk (row=c>>3, kc=(c&7)^(row&7)).
#pragma unroll
        for (int j = 0; j < 4; j++) {
            const int c = tid + 256 * j;
            const int row = c >> 3;
            const int kc = (c & 7) ^ (row & 7);
            const char* ga = x_q + (size_t)(bm0 + row) * I_DIM + k0 + kc * 16;
            __builtin_amdgcn_global_load_lds(
                (const __attribute__((address_space(1))) unsigned int*)ga,
                (__attribute__((address_space(3))) unsigned int*)(As + c * 16),
                16, 0, 0);
            const char* gb = w_q + (size_t)(bn0 + row) * I_DIM + k0 + kc * 16;
            __builtin_amdgcn_global_load_lds(
                (const __attribute__((address_space(1))) unsigned int*)gb,
                (__attribute__((address_space(3))) unsigned int*)(Bs + c * 16),
                16, 0, 0);
        }
        __syncthreads();
        // A-operand layout (i8 32x32x32): m = lane&31, k = (lane>>5)*16 + j
#pragma unroll
        for (int s = 0; s < 4; s++) {
            v4i af[2], bf[2];
#pragma unroll
            for (int mt = 0; mt < 2; mt++) {
                const int row = wm * 64 + mt * 32 + l31;
                const int kc = (s * 2 + h) ^ (row & 7);
                af[mt] = *(const v4i*)(As + row * BK + kc * 16);
            }
#pragma unroll
            for (int nt = 0; nt < 2; nt++) {
                const int row = wn * 64 + nt * 32 + l31;
                const int kc = (s * 2 + h) ^ (row & 7);
                bf[nt] = *(const v4i*)(Bs + row * BK + kc * 16);
            }
#pragma unroll
            for (int mt = 0; mt < 2; mt++)
#pragma unroll
                for (int nt = 0; nt < 2; nt++)
                    acc[mt][nt] = __builtin_amdgcn_mfma_i32_32x32x32_i8(
                        af[mt], bf[nt], acc[mt][nt], 0, 0, 0);
        }
        __syncthreads();
    }

    // epilogue: 32x32 C/D layout: col = lane&31, row = (reg&3)+8*(reg>>2)+4*(lane>>5)
#pragma unroll
    for (int mt = 0; mt < 2; mt++) {
        const int rbase = bm0 + wm * 64 + mt * 32 + 4 * h;
        float sx[16];
#pragma unroll
        for (int reg = 0; reg < 16; reg++)
            sx[reg] = scale_x[rbase + (reg & 3) + 8 * (reg >> 2)];
#pragma unroll
        for (int nt = 0; nt < 2; nt++) {
            const int oc = bn0 + wn * 64 + nt * 32 + l31;
            const float sw = scale_w[oc];
            const float bs = bias[oc];
#pragma unroll
            for (int reg = 0; reg < 16; reg++) {
                const int rr = rbase + (reg & 3) + 8 * (reg >> 2);
                out[(size_t)rr * O_DIM + oc] =
                    (float)acc[mt][nt][reg] * sx[reg] * sw + bs;
            }
        }
    }
}

// ---------------------------------------------------------------------------
extern "C" void kernel_launch(void* const* d_in, const int* in_sizes, int n_in,
                              void* d_out, int out_size, void* d_ws, size_t ws_size,
                              hipStream_t stream) {
    const float* x        = (const float*)d_in[0];
    const int*   w_packed = (const int*)d_in[1];
    const float* svd_up   = (const float*)d_in[2];
    const float* svd_down = (const float*)d_in[3];
    const float* scale    = (const float*)d_in[4];
    const float* zp       = (const float*)d_in[5];
    const float* bias     = (const float*)d_in[6];
    float* out = (float*)d_out;

    char* ws = (char*)d_ws;
    char*  w_q     = ws;                                   // 16 MB int8 [O, I]
    char*  x_q     = ws + ((size_t)16 << 20);              // 16 MB int8 [N, I]
    float* scale_w = (float*)(ws + ((size_t)32 << 20));    // 16 KB
    float* scale_x = (float*)(ws + ((size_t)32 << 20) + 16384);  // 16 KB

    quant_w_kernel<<<O_DIM / BO, 256, 0, stream>>>(w_packed, svd_up, svd_down,
                                                   scale, zp, w_q, scale_w);
    quant_x_kernel<<<N_TOK, 256, 0, stream>>>(x, x_q, scale_x);
    gemm_i8_kernel<<<(N_TOK / BM) * (O_DIM / BN), 256, 0, stream>>>(
        x_q, w_q, scale_x, scale_w, bias, out);
}